// Round 9
// baseline (895.325 us; speedup 1.0000x reference)
//
#include <hip/hip_runtime.h>
#include <hip/hip_bf16.h>
#include <math.h>

// CnnLstmCrf on MI355X, fp32-exact. Round 11: hybrid LDS+reg weights.
// r10 ("weights fully in LDS", 160,896B static) died with container-failure
// twice. Two concrete hazards fixed here without burning a diagnostic round:
//  (a) W_lds lacked __align__(16) but was accessed as float4 (ds_*_b128
//      misalignment fault risk);
//  (b) 160.9KB static LDS exceeds the 128KiB plain-HIP precedent (m201);
//      hand-built .co kernels use 160KB but hipcc-compiled ones unproven.
// Hybrid: chunks q=0..18 (76 floats/row, stride 19 quads - ODD, so b128
// reads spread 8 lanes/quad = the hardware minimum) live in LDS:
// 400*76*4 = 121,600B (+896B h buffers = 122,496 <= 128KiB precedent,
// __align__(16)). Chunks q=19..24 (24 floats) live in 6 named PINNED
// float4 regs/thread: total pressure ~50 VGPRs fits INSIDE the 64-reg tier
// the allocator insists on (r5-r8 pins failed only because 100 floats
// exceeded the grant; 24 floats do not). Weight values, dot order q=0..24,
// and nonlin text are verbatim from the passing r5-r7 kernels =>
// bit-identical tags.
// Cost model: ~140 LDS wave-reads/step (~1100cy) overlapped with ~920cy
// VALU => ~1300-1600cy/step vs ~3470 now (weight refetch through L2).
// LSTM decomposition (as r5-r7 passing): 448 threads, v=t>>2 s=t&3,
// row=s*100+v; h broadcast via one ds_read_b128 (lane q holds chunk q) +
// readlane; gates to lane 4v via 3 __shfl_xor; h double-buffered;
// ONE unconditional __syncthreads per step.
// Sizes: B=64 S=250 CL=16 CV=100 CD=300 CH=50 WD=300 FD=5
// IN=355 H=100 4H=400 HD=200 T=22 START=20 STOP=21
//
// Workspace layout (floats). lstm_out/feats alias the wrep region (dead after gemm).
#define WS_U        0          // 15000 -> pad 15360
#define WS_WPAD     15360      // 896*384 = 344064
#define WS_WREP     359424     // 16000*384 = 6144000 (reused below)
#define WS_PRE      6503424    // 16000*800 = 12800000 (end 19303424 floats = 77.2MB)
#define WS_LSTM     359424     // alias wrep: 16000*200 = 3200000 (< 6144000)
#define WS_FEATS    3559424    // alias wrep tail: 16000*22 = 352000 (ends 3911424)

// ---------------- prep: pad w_ih into [896][384] ----------------
__global__ __launch_bounds__(256) void prepw_kernel(
    const float* __restrict__ wf, const float* __restrict__ wb,
    float* __restrict__ w_pad) {
  int idx = blockIdx.x * 256 + threadIdx.x;
  if (idx >= 896 * 384) return;
  int col = idx % 384, row = idx / 384;
  float v = 0.f;
  if (col < 355) {
    if (row < 400)      v = wf[row * 355 + col];
    else if (row < 800) v = wb[(row - 400) * 355 + col];
  }
  w_pad[idx] = v;
}

// ---------------- U table: U[(c*3+k)*50+o] ----------------
__global__ __launch_bounds__(256) void u_kernel(
    const float* __restrict__ char_emb, const float* __restrict__ conv_w,
    float* __restrict__ U) {
  int idx = blockIdx.x * 256 + threadIdx.x;
  if (idx >= 15000) return;
  int c = idx / 150, rem = idx % 150, k = rem / 50, o = rem % 50;
  float acc = 0.f;
  for (int i = 0; i < 300; i++)
    acc += char_emb[c * 300 + i] * conv_w[(o * 300 + i) * 3 + k];
  U[idx] = acc;
}

// ---------------- assemble word_rep rows ----------------
__global__ __launch_bounds__(64) void assemble_kernel(
    const int* __restrict__ batch_word, const int* __restrict__ batch_feats,
    const int* __restrict__ batch_char, const int* __restrict__ recover,
    const float* __restrict__ word_emb, const float* __restrict__ feat_emb,
    const float* __restrict__ conv_b, const float* __restrict__ U,
    float* __restrict__ wrep) {
  int n = blockIdx.x;
  int tid = threadIdx.x;
  __shared__ int ch[16];
  if (tid < 16) ch[tid] = batch_char[(size_t)recover[n] * 16 + tid];
  __syncthreads();
  float* dst = wrep + (size_t)n * 384;
  int w = batch_word[n];
  for (int i = tid; i < 300; i += 64) dst[i] = word_emb[(size_t)w * 300 + i];
  if (tid < 34) {  // feat_emb (5) + zero pad (29)
    int i = 350 + tid;
    dst[i] = (i < 355) ? feat_emb[batch_feats[n] * 5 + (i - 350)] : 0.f;
  }
  if (tid < 50) {  // char CNN via U table, max over 16 positions
    int o = tid;
    float bo = conv_b[o];
    float m = -1e30f;
#pragma unroll
    for (int l = 0; l < 16; l++) {
      float v = bo + U[(ch[l] * 3 + 1) * 50 + o];
      if (l > 0)  v += U[(ch[l - 1] * 3 + 0) * 50 + o];
      if (l < 15) v += U[(ch[l + 1] * 3 + 2) * 50 + o];
      m = fmaxf(m, v);
    }
    dst[300 + o] = m;
  }
}

// ---------------- fp32 GEMM: C[16000][800] = A[16000][384] @ B[896][384]^T + bias
__global__ __launch_bounds__(256, 4) void gemm_kernel(
    const float* __restrict__ A, const float* __restrict__ B,
    float* __restrict__ C, const float* __restrict__ bf,
    const float* __restrict__ bb) {
  __shared__ float As[16][128];
  __shared__ float Bs[16][128];
  int tid = threadIdx.x;
  int m0 = blockIdx.x * 128;
  int n0 = blockIdx.y * 128;
  int tx = tid & 15, ty = tid >> 4;
  int lr = tid >> 2;
  int lc = (tid & 3) * 4;
  float acc[8][8];
#pragma unroll
  for (int i = 0; i < 8; i++)
#pragma unroll
    for (int j = 0; j < 8; j++) acc[i][j] = 0.f;

  for (int k0 = 0; k0 < 384; k0 += 16) {
#pragma unroll
    for (int h = 0; h < 2; h++) {
      int row = lr + h * 64;
      float4 av = *(const float4*)(A + (size_t)(m0 + row) * 384 + k0 + lc);
      As[lc + 0][row] = av.x; As[lc + 1][row] = av.y;
      As[lc + 2][row] = av.z; As[lc + 3][row] = av.w;
      float4 bv = *(const float4*)(B + (size_t)(n0 + row) * 384 + k0 + lc);
      Bs[lc + 0][row] = bv.x; Bs[lc + 1][row] = bv.y;
      Bs[lc + 2][row] = bv.z; Bs[lc + 3][row] = bv.w;
    }
    __syncthreads();
#pragma unroll
    for (int k = 0; k < 16; k++) {
      float a[8], b[8];
      *(float4*)&a[0] = *(const float4*)&As[k][ty * 8];
      *(float4*)&a[4] = *(const float4*)&As[k][ty * 8 + 4];
      *(float4*)&b[0] = *(const float4*)&Bs[k][tx * 8];
      *(float4*)&b[4] = *(const float4*)&Bs[k][tx * 8 + 4];
#pragma unroll
      for (int i = 0; i < 8; i++)
#pragma unroll
        for (int j = 0; j < 8; j++) acc[i][j] += a[i] * b[j];
    }
    __syncthreads();
  }
#pragma unroll
  for (int i = 0; i < 8; i++) {
    int m = m0 + ty * 8 + i;
#pragma unroll
    for (int jj = 0; jj < 8; jj++) {
      int j = n0 + tx * 8 + jj;
      if (j < 800) {
        float bias = (j < 400) ? bf[j] : bb[j - 400];
        C[(size_t)m * 800 + j] = acc[i][jj] + bias;
      }
    }
  }
}

// ---------------- BiLSTM scan: 128 blocks = (dir, row), 448 threads --------
// Weights: q=0..18 in LDS (slot t, stride 76 floats = 19 quads, odd =>
// minimal 8-lanes/quad b128 conflicts); q=19..24 in 6 pinned float4 regs.
__global__ __launch_bounds__(448) void lstm_kernel(
    const float* __restrict__ pre, const float* __restrict__ w_hh_f,
    const float* __restrict__ w_hh_b, const int* __restrict__ wordlen,
    float* __restrict__ lstm_out) {
  int t = threadIdx.x;
  int lane = t & 63;
  int dir = blockIdx.x >> 6;
  int r = blockIdx.x & 63;
  int len = wordlen[r];
  const float* __restrict__ Wh = dir ? w_hh_b : w_hh_f;
  __shared__ __align__(16) float W_lds[30400];  // 400 slots x 76 floats
  __shared__ __align__(16) float h0[112];
  __shared__ __align__(16) float h1[112];

  // Stage chunks q=0..18 of each gate row into LDS. Slot u (=4v+s) holds
  // row s*100+v; dst float4 index = slot*19+q = fidx (linear).
  {
    float4* WLv = (float4*)W_lds;
    for (int fidx = t; fidx < 7600; fidx += 448) {
      int slot = fidx / 19, q = fidx % 19;
      int grow = (slot & 3) * 100 + (slot >> 2);
      WLv[fidx] = ((const float4*)(Wh + (size_t)grow * 100))[q];
    }
  }

  const int v = t >> 2;              // hidden unit
  const int s = t & 3;               // gate: 0=i, 1=f, 2=g, 3=o
  const bool act = (v < 100);
  const int row = act ? (s * 100 + v) : 0;   // pre[] column / weight row
  const float* __restrict__ Wrow = W_lds + (act ? t : 0) * 76;

  // Chunks q=19..24 in named regs (24 floats; ~50 total pressure fits the
  // 64-reg tier => pins hold with no spill, unlike r5-r8's 100 floats).
  const float4* wrh = (const float4*)(Wh + (size_t)row * 100);
  float4 W19 = wrh[19], W20 = wrh[20], W21 = wrh[21];
  float4 W22 = wrh[22], W23 = wrh[23], W24 = wrh[24];
#define PIN4(W) asm volatile("" : "+v"(W.x), "+v"(W.y), "+v"(W.z), "+v"(W.w))
  PIN4(W19); PIN4(W20); PIN4(W21); PIN4(W22); PIN4(W23); PIN4(W24);
#undef PIN4

  if (t < 112) { h0[t] = 0.f; h1[t] = 0.f; }

  float c_reg = 0.f, h_reg = 0.f;
  const float* __restrict__ pr = pre + dir * 400;
  const int p0 = dir ? 249 : 0;
  const int dp = dir ? -1 : 1;
  const size_t rowbase = (size_t)r * 250;

  // depth-2 prefetch of this lane's pre column (steps 0 and 1)
  float pvA = 0.f, pvB = 0.f;
  if (act) {
    pvA = pr[(rowbase + (size_t)p0) * 800 + row];
    pvB = pr[(rowbase + (size_t)(p0 + dp)) * 800 + row];
  }
  const int cl = (lane < 25) ? lane : 0;  // h chunk owned by this lane
  __syncthreads();  // W_lds + h buffers ready

#define RL(x, q) __uint_as_float(__builtin_amdgcn_readlane(__float_as_uint(x), (q)))
#define DOTQL(q)                                                               \
  {                                                                            \
    const float4 wq = *(const float4*)&Wrow[4 * (q)];                          \
    g += RL(hch.x, q) * wq.x + RL(hch.y, q) * wq.y + RL(hch.z, q) * wq.z +     \
         RL(hch.w, q) * wq.w;                                                  \
  }
#define DOTQR(q, Wq)                                                           \
  g += RL(hch.x, q) * Wq.x + RL(hch.y, q) * Wq.y + RL(hch.z, q) * Wq.z +       \
       RL(hch.w, q) * Wq.w;

#define LSTM_STEP(I, HRD, HWR, PV)                                             \
  do {                                                                         \
    const int p = p0 + dp * (I);                                               \
    const bool valid = (p < len); /* block-uniform */                          \
    float g = 0.f;                                                             \
    if (valid) {                                                               \
      float4 hch = *(const float4*)&(HRD)[4 * cl];                             \
      g = PV;                                                                  \
      DOTQL(0)  DOTQL(1)  DOTQL(2)  DOTQL(3)  DOTQL(4)                         \
      DOTQL(5)  DOTQL(6)  DOTQL(7)  DOTQL(8)  DOTQL(9)                         \
      DOTQL(10) DOTQL(11) DOTQL(12) DOTQL(13) DOTQL(14)                        \
      DOTQL(15) DOTQL(16) DOTQL(17) DOTQL(18)                                  \
      DOTQR(19, W19) DOTQR(20, W20) DOTQR(21, W21)                             \
      DOTQR(22, W22) DOTQR(23, W23) DOTQR(24, W24)                             \
    }                                                                          \
    if (act) { /* keep prefetch pipeline running every step */                 \
      const int ip = ((I) + 2 < 250) ? (I) + 2 : (I);                          \
      PV = pr[(rowbase + (size_t)(p0 + dp * ip)) * 800 + row];                 \
    }                                                                          \
    if (valid) {                                                               \
      const float gf_in = __shfl_xor(g, 1, 64); /* lane 4v gets f-gate */      \
      const float gg_in = __shfl_xor(g, 2, 64); /* lane 4v gets g-gate */      \
      const float go_in = __shfl_xor(g, 3, 64); /* lane 4v gets o-gate */      \
      if (act && s == 0) {                                                     \
        const float si = 1.f / (1.f + expf(-g));                               \
        const float sf = 1.f / (1.f + expf(-gf_in));                           \
        const float so = 1.f / (1.f + expf(-go_in));                           \
        c_reg = sf * c_reg + si * tanhf(gg_in);                                \
        h_reg = so * tanhf(c_reg);                                             \
        (HWR)[v] = h_reg;                                                      \
        lstm_out[(rowbase + (size_t)p) * 200 + dir * 100 + v] = h_reg;         \
      }                                                                        \
    } else if (act && s == 0) {                                                \
      /* masked step: carry h (h_sh untouched => no race with skipped dot) */  \
      lstm_out[(rowbase + (size_t)p) * 200 + dir * 100 + v] = h_reg;           \
    }                                                                          \
    __syncthreads(); /* ONE unconditional barrier per step */                  \
  } while (0)

#pragma unroll 1
  for (int ii = 0; ii < 250; ii += 2) {
    LSTM_STEP(ii,     h0, h1, pvA);
    LSTM_STEP(ii + 1, h1, h0, pvB);
  }
#undef LSTM_STEP
#undef DOTQL
#undef DOTQR
#undef RL
}

// ---------------- projection: feats = lstm_out @ proj_w + proj_b ----------------
__global__ __launch_bounds__(256) void proj_kernel(
    const float* __restrict__ lstm_out, const float* __restrict__ proj_w,
    const float* __restrict__ proj_b, float* __restrict__ feats) {
  __shared__ float L[8][200];
  int tid = threadIdx.x;
  size_t base = (size_t)blockIdx.x * 8 * 200;
  for (int idx = tid; idx < 1600; idx += 256)
    L[idx / 200][idx % 200] = lstm_out[base + idx];
  __syncthreads();
  int ty = tid >> 5, c = tid & 31;
  if (c < 22) {
    float acc = proj_b[c];
#pragma unroll 8
    for (int k = 0; k < 200; k++) acc += L[ty][k] * proj_w[k * 22 + c];
    feats[((size_t)blockIdx.x * 8 + ty) * 22 + c] = acc;
  }
}

// ---------------- Viterbi: one wave per batch row (BORING: LDS delta) ----------
__global__ __launch_bounds__(64) void viterbi_kernel(
    const float* __restrict__ feats, const float* __restrict__ trans,
    const int* __restrict__ wordlen, int* __restrict__ out) {
  int r = blockIdx.x;
  int lane = threadIdx.x;
  __shared__ float dsh[22];          // delta (current)
  __shared__ float tsh[22][23];      // trans[k][c], padded stride 23
  __shared__ unsigned char bps[250][22];
  int len = wordlen[r];
  const float* __restrict__ fr = feats + (size_t)r * 250 * 22;
  for (int idx = lane; idx < 484; idx += 64)
    tsh[idx / 22][idx % 22] = trans[idx];
  if (lane < 22) dsh[lane] = trans[20 * 22 + lane] + fr[lane];  // START row
  __syncthreads();
  for (int t = 1; t < 250; t++) {
    float best = -1e30f, fv = 0.f;
    int arg = 0;
    if (lane < 22) {
      fv = fr[t * 22 + lane];
#pragma unroll
      for (int k = 0; k < 22; k++) {
        float cand = dsh[k] + tsh[k][lane];
        if (cand > best) { best = cand; arg = k; }  // first-max == np.argmax
      }
    }
    __syncthreads();  // all dsh reads complete
    if (lane < 22) {
      bool valid = t < len;
      if (valid) dsh[lane] = best + fv;
      bps[t][lane] = valid ? (unsigned char)arg : (unsigned char)lane;
    }
    __syncthreads();  // dsh writes visible
  }
  if (lane == 0) {
    float best = -1e30f;
    int last = 0;
#pragma unroll
    for (int k = 0; k < 22; k++) {
      float cand = dsh[k] + tsh[k][21];  // + trans[:, STOP]
      if (cand > best) { best = cand; last = k; }
    }
    int tag = last;
    out[r * 250 + 249] = tag;
    for (int t = 249; t >= 1; t--) {
      tag = bps[t][tag];
      out[r * 250 + t - 1] = tag;
    }
  }
}

extern "C" void kernel_launch(void* const* d_in, const int* in_sizes, int n_in,
                              void* d_out, int out_size, void* d_ws, size_t ws_size,
                              hipStream_t stream) {
  const int* batch_word  = (const int*)d_in[0];
  const int* batch_feats = (const int*)d_in[1];
  const int* wordlen     = (const int*)d_in[2];
  const int* batch_char  = (const int*)d_in[3];
  // d_in[4] batch_charlen: unused by reference
  const int* recover     = (const int*)d_in[5];
  // d_in[6] mask: recomputed from wordlen (bool dtype ambiguity)
  const float* char_emb  = (const float*)d_in[7];
  const float* word_emb  = (const float*)d_in[8];
  const float* feat_emb  = (const float*)d_in[9];
  const float* conv_w    = (const float*)d_in[10];
  const float* conv_b    = (const float*)d_in[11];
  const float* w_ih_f    = (const float*)d_in[12];
  const float* w_hh_f    = (const float*)d_in[13];
  const float* b_f       = (const float*)d_in[14];
  const float* w_ih_b    = (const float*)d_in[15];
  const float* w_hh_b    = (const float*)d_in[16];
  const float* b_b       = (const float*)d_in[17];
  const float* proj_w    = (const float*)d_in[18];
  const float* proj_b    = (const float*)d_in[19];
  const float* trans     = (const float*)d_in[20];
  int* out = (int*)d_out;
  float* ws = (float*)d_ws;

  float* U        = ws + WS_U;
  float* w_pad    = ws + WS_WPAD;
  float* wrep     = ws + WS_WREP;
  float* pre      = ws + WS_PRE;
  float* lstm_out = ws + WS_LSTM;   // aliases wrep (dead after gemm)
  float* feats    = ws + WS_FEATS;  // aliases wrep tail

  prepw_kernel<<<1344, 256, 0, stream>>>(w_ih_f, w_ih_b, w_pad);
  u_kernel<<<59, 256, 0, stream>>>(char_emb, conv_w, U);
  assemble_kernel<<<16000, 64, 0, stream>>>(batch_word, batch_feats, batch_char,
                                            recover, word_emb, feat_emb, conv_b,
                                            U, wrep);
  dim3 ggrid(125, 7);
  gemm_kernel<<<ggrid, 256, 0, stream>>>(wrep, w_pad, pre, b_f, b_b);
  lstm_kernel<<<128, 448, 0, stream>>>(pre, w_hh_f, w_hh_b, wordlen, lstm_out);
  proj_kernel<<<2000, 256, 0, stream>>>(lstm_out, proj_w, proj_b, feats);
  viterbi_kernel<<<64, 64, 0, stream>>>(feats, trans, wordlen, out);
}

// Round 10
// 860.857 us; speedup vs baseline: 1.0400x; 1.0400x over previous
//
#include <hip/hip_runtime.h>
#include <hip/hip_bf16.h>
#include <math.h>

// CnnLstmCrf on MI355X, fp32-exact. Round 12: K-split (r9, passed) + small
// reg/LDS weight hybrid sized to the allocator's DEMONSTRATED grant.
// Cross-round evidence: grant is 64-88 VGPR no matter what (r5-r11);
// ~24 pinned floats hold (r11), 52+ spill (r9: SGPR 112 tell). And full-LDS
// weights (r11) expose ds_read LATENCY (~120cy) at 1.75 waves/SIMD.
// Fix both: 896 threads (14 waves = 3.5/SIMD TLP) x 13 quads/thread, split
// 9 quads in named+pinned regs (36 floats; fits even a 64 grant) + 4 quads
// in LDS at stride 20 dwords (80B: 16B-aligned b128, 20l%32 covers 8
// bank-quads = b128 conflict floor). Per-step LDS weight reads: 3.5 avg
// per thread (49 wave-b128 ~ 600cy, hidden by TLP) vs r11's 19.
// No occupancy attributes (r9's (3,4) self-capped to 64).
// Numerics: dot order q=0..24 and nonlin text verbatim from r9 (passed,
// absmax 0) => bit-identical tags.
// Structure (= r9): waves 0-6 group 0 (quads 0-12 + pre seed), waves 7-13
// group 1 (quads 13-24, partial -> g_sh); u=(w%7)*64+lane, v=u>>2, s=u&3,
// row=s*100+v; h broadcast via ds_read_b128 (lane q holds chunk q) +
// readlane; combine via g_sh[400]; 2 plain __syncthreads per step.
// Sizes: B=64 S=250 CL=16 CV=100 CD=300 CH=50 WD=300 FD=5
// IN=355 H=100 4H=400 HD=200 T=22 START=20 STOP=21
//
// Workspace layout (floats). lstm_out/feats alias the wrep region (dead after gemm).
#define WS_U        0          // 15000 -> pad 15360
#define WS_WPAD     15360      // 896*384 = 344064
#define WS_WREP     359424     // 16000*384 = 6144000 (reused below)
#define WS_PRE      6503424    // 16000*800 = 12800000 (end 19303424 floats = 77.2MB)
#define WS_LSTM     359424     // alias wrep: 16000*200 = 3200000 (< 6144000)
#define WS_FEATS    3559424    // alias wrep tail: 16000*22 = 352000 (ends 3911424)

// ---------------- prep: pad w_ih into [896][384] ----------------
__global__ __launch_bounds__(256) void prepw_kernel(
    const float* __restrict__ wf, const float* __restrict__ wb,
    float* __restrict__ w_pad) {
  int idx = blockIdx.x * 256 + threadIdx.x;
  if (idx >= 896 * 384) return;
  int col = idx % 384, row = idx / 384;
  float v = 0.f;
  if (col < 355) {
    if (row < 400)      v = wf[row * 355 + col];
    else if (row < 800) v = wb[(row - 400) * 355 + col];
  }
  w_pad[idx] = v;
}

// ---------------- U table: U[(c*3+k)*50+o] ----------------
__global__ __launch_bounds__(256) void u_kernel(
    const float* __restrict__ char_emb, const float* __restrict__ conv_w,
    float* __restrict__ U) {
  int idx = blockIdx.x * 256 + threadIdx.x;
  if (idx >= 15000) return;
  int c = idx / 150, rem = idx % 150, k = rem / 50, o = rem % 50;
  float acc = 0.f;
  for (int i = 0; i < 300; i++)
    acc += char_emb[c * 300 + i] * conv_w[(o * 300 + i) * 3 + k];
  U[idx] = acc;
}

// ---------------- assemble word_rep rows ----------------
__global__ __launch_bounds__(64) void assemble_kernel(
    const int* __restrict__ batch_word, const int* __restrict__ batch_feats,
    const int* __restrict__ batch_char, const int* __restrict__ recover,
    const float* __restrict__ word_emb, const float* __restrict__ feat_emb,
    const float* __restrict__ conv_b, const float* __restrict__ U,
    float* __restrict__ wrep) {
  int n = blockIdx.x;
  int tid = threadIdx.x;
  __shared__ int ch[16];
  if (tid < 16) ch[tid] = batch_char[(size_t)recover[n] * 16 + tid];
  __syncthreads();
  float* dst = wrep + (size_t)n * 384;
  int w = batch_word[n];
  for (int i = tid; i < 300; i += 64) dst[i] = word_emb[(size_t)w * 300 + i];
  if (tid < 34) {  // feat_emb (5) + zero pad (29)
    int i = 350 + tid;
    dst[i] = (i < 355) ? feat_emb[batch_feats[n] * 5 + (i - 350)] : 0.f;
  }
  if (tid < 50) {  // char CNN via U table, max over 16 positions
    int o = tid;
    float bo = conv_b[o];
    float m = -1e30f;
#pragma unroll
    for (int l = 0; l < 16; l++) {
      float v = bo + U[(ch[l] * 3 + 1) * 50 + o];
      if (l > 0)  v += U[(ch[l - 1] * 3 + 0) * 50 + o];
      if (l < 15) v += U[(ch[l + 1] * 3 + 2) * 50 + o];
      m = fmaxf(m, v);
    }
    dst[300 + o] = m;
  }
}

// ---------------- fp32 GEMM: C[16000][800] = A[16000][384] @ B[896][384]^T + bias
__global__ __launch_bounds__(256, 4) void gemm_kernel(
    const float* __restrict__ A, const float* __restrict__ B,
    float* __restrict__ C, const float* __restrict__ bf,
    const float* __restrict__ bb) {
  __shared__ float As[16][128];
  __shared__ float Bs[16][128];
  int tid = threadIdx.x;
  int m0 = blockIdx.x * 128;
  int n0 = blockIdx.y * 128;
  int tx = tid & 15, ty = tid >> 4;
  int lr = tid >> 2;
  int lc = (tid & 3) * 4;
  float acc[8][8];
#pragma unroll
  for (int i = 0; i < 8; i++)
#pragma unroll
    for (int j = 0; j < 8; j++) acc[i][j] = 0.f;

  for (int k0 = 0; k0 < 384; k0 += 16) {
#pragma unroll
    for (int h = 0; h < 2; h++) {
      int row = lr + h * 64;
      float4 av = *(const float4*)(A + (size_t)(m0 + row) * 384 + k0 + lc);
      As[lc + 0][row] = av.x; As[lc + 1][row] = av.y;
      As[lc + 2][row] = av.z; As[lc + 3][row] = av.w;
      float4 bv = *(const float4*)(B + (size_t)(n0 + row) * 384 + k0 + lc);
      Bs[lc + 0][row] = bv.x; Bs[lc + 1][row] = bv.y;
      Bs[lc + 2][row] = bv.z; Bs[lc + 3][row] = bv.w;
    }
    __syncthreads();
#pragma unroll
    for (int k = 0; k < 16; k++) {
      float a[8], b[8];
      *(float4*)&a[0] = *(const float4*)&As[k][ty * 8];
      *(float4*)&a[4] = *(const float4*)&As[k][ty * 8 + 4];
      *(float4*)&b[0] = *(const float4*)&Bs[k][tx * 8];
      *(float4*)&b[4] = *(const float4*)&Bs[k][tx * 8 + 4];
#pragma unroll
      for (int i = 0; i < 8; i++)
#pragma unroll
        for (int j = 0; j < 8; j++) acc[i][j] += a[i] * b[j];
    }
    __syncthreads();
  }
#pragma unroll
  for (int i = 0; i < 8; i++) {
    int m = m0 + ty * 8 + i;
#pragma unroll
    for (int jj = 0; jj < 8; jj++) {
      int j = n0 + tx * 8 + jj;
      if (j < 800) {
        float bias = (j < 400) ? bf[j] : bb[j - 400];
        C[(size_t)m * 800 + j] = acc[i][jj] + bias;
      }
    }
  }
}

// ---------------- BiLSTM scan: 128 blocks = (dir, row), 896 threads --------
// K-split: waves 0-6 quads 0-12 (+pre seed), waves 7-13 quads 13-24.
// Weights: 9 quads in pinned regs + up to 4 quads in LDS (stride 20 dwords).
__global__ __launch_bounds__(896) void lstm_kernel(
    const float* __restrict__ pre, const float* __restrict__ w_hh_f,
    const float* __restrict__ w_hh_b, const int* __restrict__ wordlen,
    float* __restrict__ lstm_out) {
  int t = threadIdx.x;
  int lane = t & 63;
  int w = t >> 6;                    // wave 0..13
  int grp = (w >= 7) ? 1 : 0;        // K-half (wave-uniform)
  int u = (w - grp * 7) * 64 + lane; // 0..447 within group
  int dir = blockIdx.x >> 6;
  int r = blockIdx.x & 63;
  int len = wordlen[r];
  const float* __restrict__ Wh = dir ? w_hh_b : w_hh_f;
  __shared__ __align__(16) float W_lds[17920];  // 896 threads x 20 dwords
  __shared__ __align__(16) float h0[112];
  __shared__ __align__(16) float h1[112];
  __shared__ float g_sh[400];

  const int v = u >> 2;              // hidden unit
  const int s = u & 3;               // gate: 0=i, 1=f, 2=g, 3=o
  const bool act = (v < 100);
  const int row = act ? (s * 100 + v) : 0;
  const bool g0act = (grp == 0) && act;

  // Reg weights: 9 quads starting at this group's K-base.
  const float4* wrh = (const float4*)(Wh + (size_t)row * 100) + (grp ? 13 : 0);
  float4 W00 = wrh[0], W01 = wrh[1], W02 = wrh[2];
  float4 W03 = wrh[3], W04 = wrh[4], W05 = wrh[5];
  float4 W06 = wrh[6], W07 = wrh[7], W08 = wrh[8];
#define PIN4(W) asm volatile("" : "+v"(W.x), "+v"(W.y), "+v"(W.z), "+v"(W.w))
  PIN4(W00); PIN4(W01); PIN4(W02); PIN4(W03); PIN4(W04);
  PIN4(W05); PIN4(W06); PIN4(W07); PIN4(W08);
#undef PIN4

  // LDS weights: group 0 quads 9..12 (4), group 1 quads 22..24 (3, pad 1).
  {
    const int nq = grp ? 3 : 4;
    float4* dst = (float4*)(W_lds + t * 20);
    for (int j = 0; j < 4; j++)
      dst[j] = (act && j < nq) ? wrh[9 + j] : make_float4(0.f, 0.f, 0.f, 0.f);
  }

  if (t < 112) { h0[t] = 0.f; h1[t] = 0.f; }

  float c_reg = 0.f, h_reg = 0.f;
  const float* __restrict__ pr = pre + dir * 400;
  const int p0 = dir ? 249 : 0;
  const int dp = dir ? -1 : 1;
  const size_t rowbase = (size_t)r * 250;

  // depth-1 prefetch of this thread's pre column (group 0 only)
  float pv = 0.f;
  if (g0act) pv = pr[(rowbase + (size_t)p0) * 800 + row];
  const int cl = (lane < 25) ? lane : 0;  // h chunk owned by this lane
  __syncthreads();  // W_lds + h buffers + weights ready

#define RL(x, q) __uint_as_float(__builtin_amdgcn_readlane(__float_as_uint(x), (q)))
#define DOTQR(q, Wq)                                                           \
  g += RL(hch.x, q) * Wq.x + RL(hch.y, q) * Wq.y + RL(hch.z, q) * Wq.z +       \
       RL(hch.w, q) * Wq.w;
#define DOTQL(q, j)                                                            \
  {                                                                            \
    const float4 wq = *(const float4*)&W_lds[t * 20 + 4 * (j)];                \
    g += RL(hch.x, q) * wq.x + RL(hch.y, q) * wq.y + RL(hch.z, q) * wq.z +     \
         RL(hch.w, q) * wq.w;                                                  \
  }

#define LSTM_STEP(I, HRD, HWR)                                                 \
  do {                                                                         \
    const int p = p0 + dp * (I);                                               \
    const bool valid = (p < len); /* block-uniform */                          \
    float pvN = 0.f;                                                           \
    if (g0act) { /* issue next step's pre load BEFORE the dot */               \
      const int ip = ((I) + 1 < 250) ? (I) + 1 : (I);                          \
      pvN = pr[(rowbase + (size_t)(p0 + dp * ip)) * 800 + row];                \
    }                                                                          \
    float g = 0.f;                                                             \
    if (valid) {                                                               \
      float4 hch = *(const float4*)&(HRD)[4 * cl];                             \
      if (grp == 0) {                                                          \
        g = pv;                                                                \
        DOTQR(0, W00)  DOTQR(1, W01)  DOTQR(2, W02)  DOTQR(3, W03)             \
        DOTQR(4, W04)  DOTQR(5, W05)  DOTQR(6, W06)  DOTQR(7, W07)             \
        DOTQR(8, W08)                                                          \
        DOTQL(9, 0)  DOTQL(10, 1)  DOTQL(11, 2)  DOTQL(12, 3)                  \
      } else {                                                                 \
        DOTQR(13, W00) DOTQR(14, W01) DOTQR(15, W02) DOTQR(16, W03)            \
        DOTQR(17, W04) DOTQR(18, W05) DOTQR(19, W06) DOTQR(20, W07)            \
        DOTQR(21, W08)                                                         \
        DOTQL(22, 0) DOTQL(23, 1) DOTQL(24, 2)                                 \
        if (act) g_sh[row] = g;                                                \
      }                                                                        \
    }                                                                          \
    pv = pvN;                                                                  \
    __syncthreads(); /* B1: g_sh(hi) visible; h reads of this step done */     \
    if (valid) {                                                               \
      if (grp == 0) {                                                          \
        const float gfull = g + g_sh[row];                                     \
        const float gf_in = __shfl_xor(gfull, 1, 64); /* f-gate */             \
        const float gg_in = __shfl_xor(gfull, 2, 64); /* g-gate */             \
        const float go_in = __shfl_xor(gfull, 3, 64); /* o-gate */             \
        if (act && s == 0) {                                                   \
          const float si = 1.f / (1.f + expf(-gfull));                         \
          const float sf = 1.f / (1.f + expf(-gf_in));                         \
          const float so = 1.f / (1.f + expf(-go_in));                         \
          c_reg = sf * c_reg + si * tanhf(gg_in);                              \
          h_reg = so * tanhf(c_reg);                                           \
          (HWR)[v] = h_reg;                                                    \
          lstm_out[(rowbase + (size_t)p) * 200 + dir * 100 + v] = h_reg;       \
        }                                                                      \
      }                                                                        \
    } else if (g0act && s == 0) {                                              \
      /* masked step: carry h; buffers untouched */                            \
      lstm_out[(rowbase + (size_t)p) * 200 + dir * 100 + v] = h_reg;           \
    }                                                                          \
    __syncthreads(); /* B2: h(HWR) visible; g_sh reads done */                 \
  } while (0)

#pragma unroll 1
  for (int ii = 0; ii < 250; ii += 2) {
    LSTM_STEP(ii,     h0, h1);
    LSTM_STEP(ii + 1, h1, h0);
  }
#undef LSTM_STEP
#undef DOTQR
#undef DOTQL
#undef RL
}

// ---------------- projection: feats = lstm_out @ proj_w + proj_b ----------------
__global__ __launch_bounds__(256) void proj_kernel(
    const float* __restrict__ lstm_out, const float* __restrict__ proj_w,
    const float* __restrict__ proj_b, float* __restrict__ feats) {
  __shared__ float L[8][200];
  int tid = threadIdx.x;
  size_t base = (size_t)blockIdx.x * 8 * 200;
  for (int idx = tid; idx < 1600; idx += 256)
    L[idx / 200][idx % 200] = lstm_out[base + idx];
  __syncthreads();
  int ty = tid >> 5, c = tid & 31;
  if (c < 22) {
    float acc = proj_b[c];
#pragma unroll 8
    for (int k = 0; k < 200; k++) acc += L[ty][k] * proj_w[k * 22 + c];
    feats[((size_t)blockIdx.x * 8 + ty) * 22 + c] = acc;
  }
}

// ---------------- Viterbi: one wave per batch row (BORING: LDS delta) ----------
__global__ __launch_bounds__(64) void viterbi_kernel(
    const float* __restrict__ feats, const float* __restrict__ trans,
    const int* __restrict__ wordlen, int* __restrict__ out) {
  int r = blockIdx.x;
  int lane = threadIdx.x;
  __shared__ float dsh[22];          // delta (current)
  __shared__ float tsh[22][23];      // trans[k][c], padded stride 23
  __shared__ unsigned char bps[250][22];
  int len = wordlen[r];
  const float* __restrict__ fr = feats + (size_t)r * 250 * 22;
  for (int idx = lane; idx < 484; idx += 64)
    tsh[idx / 22][idx % 22] = trans[idx];
  if (lane < 22) dsh[lane] = trans[20 * 22 + lane] + fr[lane];  // START row
  __syncthreads();
  for (int t = 1; t < 250; t++) {
    float best = -1e30f, fv = 0.f;
    int arg = 0;
    if (lane < 22) {
      fv = fr[t * 22 + lane];
#pragma unroll
      for (int k = 0; k < 22; k++) {
        float cand = dsh[k] + tsh[k][lane];
        if (cand > best) { best = cand; arg = k; }  // first-max == np.argmax
      }
    }
    __syncthreads();  // all dsh reads complete
    if (lane < 22) {
      bool valid = t < len;
      if (valid) dsh[lane] = best + fv;
      bps[t][lane] = valid ? (unsigned char)arg : (unsigned char)lane;
    }
    __syncthreads();  // dsh writes visible
  }
  if (lane == 0) {
    float best = -1e30f;
    int last = 0;
#pragma unroll
    for (int k = 0; k < 22; k++) {
      float cand = dsh[k] + tsh[k][21];  // + trans[:, STOP]
      if (cand > best) { best = cand; last = k; }
    }
    int tag = last;
    out[r * 250 + 249] = tag;
    for (int t = 249; t >= 1; t--) {
      tag = bps[t][tag];
      out[r * 250 + t - 1] = tag;
    }
  }
}

extern "C" void kernel_launch(void* const* d_in, const int* in_sizes, int n_in,
                              void* d_out, int out_size, void* d_ws, size_t ws_size,
                              hipStream_t stream) {
  const int* batch_word  = (const int*)d_in[0];
  const int* batch_feats = (const int*)d_in[1];
  const int* wordlen     = (const int*)d_in[2];
  const int* batch_char  = (const int*)d_in[3];
  // d_in[4] batch_charlen: unused by reference
  const int* recover     = (const int*)d_in[5];
  // d_in[6] mask: recomputed from wordlen (bool dtype ambiguity)
  const float* char_emb  = (const float*)d_in[7];
  const float* word_emb  = (const float*)d_in[8];
  const float* feat_emb  = (const float*)d_in[9];
  const float* conv_w    = (const float*)d_in[10];
  const float* conv_b    = (const float*)d_in[11];
  const float* w_ih_f    = (const float*)d_in[12];
  const float* w_hh_f    = (const float*)d_in[13];
  const float* b_f       = (const float*)d_in[14];
  const float* w_ih_b    = (const float*)d_in[15];
  const float* w_hh_b    = (const float*)d_in[16];
  const float* b_b       = (const float*)d_in[17];
  const float* proj_w    = (const float*)d_in[18];
  const float* proj_b    = (const float*)d_in[19];
  const float* trans     = (const float*)d_in[20];
  int* out = (int*)d_out;
  float* ws = (float*)d_ws;

  float* U        = ws + WS_U;
  float* w_pad    = ws + WS_WPAD;
  float* wrep     = ws + WS_WREP;
  float* pre      = ws + WS_PRE;
  float* lstm_out = ws + WS_LSTM;   // aliases wrep (dead after gemm)
  float* feats    = ws + WS_FEATS;  // aliases wrep tail

  prepw_kernel<<<1344, 256, 0, stream>>>(w_ih_f, w_ih_b, w_pad);
  u_kernel<<<59, 256, 0, stream>>>(char_emb, conv_w, U);
  assemble_kernel<<<16000, 64, 0, stream>>>(batch_word, batch_feats, batch_char,
                                            recover, word_emb, feat_emb, conv_b,
                                            U, wrep);
  dim3 ggrid(125, 7);
  gemm_kernel<<<ggrid, 256, 0, stream>>>(wrep, w_pad, pre, b_f, b_b);
  lstm_kernel<<<128, 896, 0, stream>>>(pre, w_hh_f, w_hh_b, wordlen, lstm_out);
  proj_kernel<<<2000, 256, 0, stream>>>(lstm_out, proj_w, proj_b, feats);
  viterbi_kernel<<<64, 64, 0, stream>>>(feats, trans, wordlen, out);
}